// Round 6
// baseline (388.088 us; speedup 1.0000x reference)
//
#include <hip/hip_runtime.h>

// ---------------------------------------------------------------------------
// MultiheadAttention: T=1024, B=8, E=1024, H=16, HD=64, SCALE=0.125
// R11: back to R8's proven k_attn staging (R10's 0-conflict async pipeline
//     was net -8%: conflicts were already free, pipeline added spill).
//     k_attn chain cut: per-lane PARTIAL row-sum (al is row-uniform, so the
//     4-shfl sum reduce moves from every iter to the epilogue: -16 DS
//     round-trips and ~-160cy serial chain per iter) + explicit max tree.
//     GEMMs: XCD-chunked blockIdx swizzle (T1, grids 1536/512 both %8==0)
//     -> per-XCD A-panel L2 residency. 4x k_transw fused into one launch.
// ---------------------------------------------------------------------------

typedef __bf16 bf16x8 __attribute__((ext_vector_type(8)));
typedef float f32x4 __attribute__((ext_vector_type(4)));

#define LOG2E 1.4426950408889634f
#define QSCALE 0.18033688011112042f  // 0.125 * LOG2E

// round-to-nearest-even (one-time prep kernels)
static __device__ __forceinline__ unsigned short f2bf_rn(float f) {
  union { float f; unsigned u; } x;
  x.f = f;
  unsigned r = (x.u + 0x7fffu + ((x.u >> 16) & 1u)) >> 16;
  return (unsigned short)r;
}
// round-half-up (hot paths: 2 VALU ops)
static __device__ __forceinline__ unsigned short f2bf(float f) {
  union { float f; unsigned u; } x;
  x.f = f;
  return (unsigned short)((x.u + 0x8000u) >> 16);
}

static __device__ __forceinline__ void async_cp16(const void* g, void* l) {
  __builtin_amdgcn_global_load_lds((__attribute__((address_space(1))) void*)g,
                                   (__attribute__((address_space(3))) void*)l,
                                   16, 0, 0);
}

// ---------------- fp32 -> bf16 convert (query) ----------------
__global__ void k_cvt(const float* __restrict__ src, unsigned short* __restrict__ dst) {
  const int idx = blockIdx.x * 256 + threadIdx.x;
  const float4 f = ((const float4*)src)[idx];
  unsigned lo = (unsigned)f2bf_rn(f.x) | ((unsigned)f2bf_rn(f.y) << 16);
  unsigned hi = (unsigned)f2bf_rn(f.z) | ((unsigned)f2bf_rn(f.w) << 16);
  uint2 v; v.x = lo; v.y = hi;
  *(uint2*)(dst + (size_t)idx * 4) = v;
}

// ---------------- mask -> additive float (0 / -1e30) ----------------
__global__ void k_mask(const int* __restrict__ mask, float* __restrict__ Mfg) {
  const int i = blockIdx.x * 256 + threadIdx.x;  // 8192 total
  Mfg[i] = mask[i] ? -1e30f : 0.f;
}

// ---------------- transpose + convert 4 weights in one launch --------------
__global__ void k_transw4(const float* __restrict__ wq, const float* __restrict__ wk,
                          const float* __restrict__ wv, const float* __restrict__ wo,
                          unsigned short* __restrict__ d_qkv,
                          unsigned short* __restrict__ d_o) {
  __shared__ float tile[32][33];
  const int z = blockIdx.z;
  const float* src = (z == 0) ? wq : (z == 1) ? wk : (z == 2) ? wv : wo;
  unsigned short* dst = (z < 3) ? d_qkv + (size_t)z * 1024 * 1024 : d_o;
  const int bx = blockIdx.x << 5;
  const int by = blockIdx.y << 5;
  const int tx = threadIdx.x, ty = threadIdx.y;
#pragma unroll
  for (int i = 0; i < 32; i += 8)
    tile[ty + i][tx] = src[(size_t)(by + ty + i) * 1024 + bx + tx];
  __syncthreads();
#pragma unroll
  for (int i = 0; i < 32; i += 8)
    dst[(size_t)(bx + ty + i) * 1024 + by + tx] = f2bf_rn(tile[tx][ty + i]);
}

// ---------------- bias pretransform: fragment-layout bf16, log2 domain -----
__global__ __launch_bounds__(256, 2) void k_biasT(const float* __restrict__ bias,
                                                  unsigned short* __restrict__ B2) {
  __shared__ unsigned short tile[128 * 132];
  const int tid = threadIdx.x;
  const int ss = blockIdx.x, tt = blockIdx.y, h = blockIdx.z;
  const float* src = bias + ((long)h * 1024 + tt * 128) * 1024 + ss * 128;
#pragma unroll
  for (int c = 0; c < 16; ++c) {
    int flat = c * 256 + tid;
    int row = flat >> 5, col = (flat & 31) << 2;
    float4 v = *(const float4*)(src + (long)row * 1024 + col);
    unsigned short* t4 = &tile[row * 132 + col];
    t4[0] = f2bf_rn(v.x * LOG2E); t4[1] = f2bf_rn(v.y * LOG2E);
    t4[2] = f2bf_rn(v.z * LOG2E); t4[3] = f2bf_rn(v.w * LOG2E);
  }
  __syncthreads();
  const int wid = tid >> 6, lane = tid & 63, lanelo = lane & 15, quad = lane >> 4;
  unsigned short outv[64];
#pragma unroll
  for (int mi = 0; mi < 2; ++mi)
#pragma unroll
    for (int nj = 0; nj < 8; ++nj)
#pragma unroll
      for (int r = 0; r < 4; ++r)
        outv[mi * 32 + nj * 4 + r] =
            tile[(wid * 32 + mi * 16 + quad * 4 + r) * 132 + nj * 16 + lanelo];
  unsigned short* dst = B2 + ((((long)(h * 8 + tt) * 8 + ss) * 256 + tid) << 6);
#pragma unroll
  for (int i = 0; i < 8; ++i) ((uint4*)dst)[i] = ((const uint4*)outv)[i];
}

// ---------------- 128x128 bf16 GEMM mainloop (m97 structure) ----------------
static __device__ __forceinline__ void gemm_tile_128x128(
    const unsigned short* __restrict__ A, const unsigned short* __restrict__ Bt,
    int K, long m0, long n0,
    unsigned short* As, unsigned short* Bs, f32x4 acc[4][4]) {
  const int tid = threadIdx.x;
  const int wid = tid >> 6;
  const int lane = tid & 63;
  const int lanelo = lane & 15;
  const int quad = lane >> 4;
  const int wm = (wid >> 1) << 6;
  const int wn = (wid & 1) << 6;
  const int srow = tid >> 2;
  const int scol = (tid & 3) << 3;

  for (int k0 = 0; k0 < K; k0 += 32) {
    __syncthreads();
    {
      const unsigned short* ga0 = A + (m0 + srow) * K + k0 + scol;
      const unsigned short* ga1 = A + (m0 + srow + 64) * K + k0 + scol;
      const unsigned short* gb0 = Bt + (n0 + srow) * K + k0 + scol;
      const unsigned short* gb1 = Bt + (n0 + srow + 64) * K + k0 + scol;
      char* la = (char*)As + wid * 1024;
      char* lb = (char*)Bs + wid * 1024;
      async_cp16(ga0, la);
      async_cp16(ga1, la + 4096);
      async_cp16(gb0, lb);
      async_cp16(gb1, lb + 4096);
    }
    __syncthreads();
    bf16x8 a[4], b[4];
#pragma unroll
    for (int i = 0; i < 4; ++i) {
      a[i] = *(const bf16x8*)(As + (wm + i * 16 + lanelo) * 32 + quad * 8);
      b[i] = *(const bf16x8*)(Bs + (wn + i * 16 + lanelo) * 32 + quad * 8);
    }
#pragma unroll
    for (int i = 0; i < 4; ++i)
#pragma unroll
      for (int j = 0; j < 4; ++j)
        acc[i][j] = __builtin_amdgcn_mfma_f32_16x16x32_bf16(a[i], b[j], acc[i][j], 0, 0, 0);
  }
}

// ---------------- QKV GEMM with scatter epilogue ----------------
// Qh/Kh: [bh][t][64] bf16 (Q pre-scaled by 0.125*LOG2E); Vt: [bh][d][1024].
// XCD swizzle: 1536 blocks, chunk 192/XCD -> 8 m-rows (2MB A-panel) per L2.
__global__ __launch_bounds__(256, 2) void k_gemm_qkv(
    const unsigned short* __restrict__ A, const unsigned short* __restrict__ Bt,
    unsigned short* __restrict__ Qh, unsigned short* __restrict__ Kh,
    unsigned short* __restrict__ Vt) {
  __shared__ unsigned short smem[9216];  // As(4096) + Bs(4096); V-epilogue reuses [128][72]
  unsigned short* As = smem;
  unsigned short* Bs = smem + 4096;
  f32x4 acc[4][4];
  const f32x4 z4 = {0.f, 0.f, 0.f, 0.f};
#pragma unroll
  for (int i = 0; i < 4; ++i)
#pragma unroll
    for (int j = 0; j < 4; ++j) acc[i][j] = z4;

  const int flat = blockIdx.y * 24 + blockIdx.x;        // HW dispatch order
  const int swz = (flat & 7) * 192 + (flat >> 3);       // bijective (1536%8==0)
  const int bx = swz % 24, by = swz / 24;
  const long m0 = (long)by * 128;
  const long n0 = (long)bx * 128;
  gemm_tile_128x128(A, Bt, 1024, m0, n0, As, Bs, acc);

  const int tid = threadIdx.x;
  const int wid = tid >> 6;
  const int lane = tid & 63;
  const int lanelo = lane & 15;
  const int quad = lane >> 4;
  const int wm = (wid >> 1) << 6;
  const int wn = (wid & 1) << 6;
  const int which = bx >> 3;  // 0:Q 1:K 2:V

  if (which == 2) {
    // V epilogue: LDS transpose -> 32B-run coalesced stores into Vt[bh][d][1024]
    unsigned short* Vt_s = smem;  // [128][72]
    const long t0g = m0 >> 3;
#pragma unroll
    for (int half = 0; half < 2; ++half) {
      __syncthreads();
      if ((wid & 1) == half) {
#pragma unroll
        for (int mi = 0; mi < 4; ++mi)
#pragma unroll
          for (int nj = 0; nj < 4; ++nj)
#pragma unroll
            for (int r = 0; r < 4; ++r)
              Vt_s[(wm + mi * 16 + quad * 4 + r) * 72 + nj * 16 + lanelo] =
                  f2bf(acc[mi][nj][r]);
      }
      __syncthreads();
      const int h = (((int)(n0 & 1023)) >> 6) + half;
#pragma unroll
      for (int pp = 0; pp < 2; ++pp) {
        int p = tid + pp * 256;
        int b = p >> 6, d = p & 63;
        long off = ((long)(b * 16 + h)) << 16;
        __attribute__((aligned(16))) unsigned short vals[16];
#pragma unroll
        for (int t = 0; t < 16; ++t) vals[t] = Vt_s[(t * 8 + b) * 72 + d];
        uint4* dst = (uint4*)(Vt + off + (long)d * 1024 + t0g);
        dst[0] = ((const uint4*)vals)[0];
        dst[1] = ((const uint4*)vals)[1];
      }
    }
  } else {
#pragma unroll
    for (int mi = 0; mi < 4; ++mi)
#pragma unroll
      for (int nj = 0; nj < 4; ++nj)
#pragma unroll
        for (int r = 0; r < 4; ++r) {
          int m = (int)m0 + wm + mi * 16 + quad * 4 + r;
          int n = (int)n0 + wn + nj * 16 + lanelo;
          float v = acc[mi][nj][r];
          int t = m >> 3, b = m & 7;
          int e = n & 1023, h = e >> 6, d = e & 63;
          long off = ((long)(b * 16 + h)) << 16;
          if (which == 0)
            Qh[off + t * 64 + d] = f2bf(v * QSCALE);
          else
            Kh[off + t * 64 + d] = f2bf(v);
        }
  }
}

// ---------------- flash attention (log2-domain, 512 thr / 16 rows per wave)
// grid: (128 bh, 8 t-tiles) — same-bh blocks share flat%8 -> same XCD L2.
__global__ __launch_bounds__(512, 4) void k_attn(
    const unsigned short* __restrict__ Qh, const unsigned short* __restrict__ Kh,
    const unsigned short* __restrict__ Vt, const unsigned short* __restrict__ B2,
    const float* __restrict__ Mfg, unsigned short* __restrict__ A2) {
  __shared__ unsigned short Ks[128 * 72];  // [s_loc][64+8 pad]   18432 B
  __shared__ unsigned short Vs[64 * 136];  // [d][128+8 pad]      17408 B
  __shared__ unsigned short Ps[128 * 72];  // [t_loc][64+8 pad]   18432 B

  const int tid = threadIdx.x;
  const int wid = tid >> 6;        // 0..7
  const int lane = tid & 63;
  const int lanelo = lane & 15;
  const int quad = lane >> 4;
  const int bh = blockIdx.x;
  const int b = bh >> 4, h = bh & 15;
  const int tt = blockIdx.y;
  const int t0 = tt * 128;
  const long head = (long)bh << 16;

  // Q fragments straight from global (pre-scaled by 0.125*LOG2E): 16 rows/wave
  bf16x8 aq[2];
#pragma unroll
  for (int ks = 0; ks < 2; ++ks)
    aq[ks] = *(const bf16x8*)(Qh + head +
                              (long)(t0 + wid * 16 + lanelo) * 64 +
                              ks * 32 + quad * 8);

  const f32x4 z4 = {0.f, 0.f, 0.f, 0.f};
  f32x4 Oacc[4];
#pragma unroll
  for (int dj = 0; dj < 4; ++dj) Oacc[dj] = z4;
  float mrow[4], lrow[4];  // lrow = PER-LANE PARTIAL sum (reduced at epilogue)
#pragma unroll
  for (int r = 0; r < 4; ++r) { mrow[r] = -1e30f; lrow[r] = 0.f; }

  // bias fragment base: B2 laid out for 256-thr blocks with 2 mi-frags/thread;
  // wave pair (wid>>1) = old wid, (wid&1) = old mi.
  const long biasbase = (((long)(h * 8 + tt) * 8) * 256 + (wid >> 1) * 64 + lane) * 64 +
                        (wid & 1) * 32;

  for (int s0 = 0; s0 < 1024; s0 += 128) {
    // bias + mask loads: independent, issued before barriers for overlap
    bf16x8 bfr[4];
    {
      const bf16x8* bp8 = (const bf16x8*)(B2 + biasbase + ((long)(s0 >> 7) * 256 << 6));
#pragma unroll
      for (int i = 0; i < 4; ++i) bfr[i] = bp8[i];
    }
    float madd[8];
#pragma unroll
    for (int nj = 0; nj < 8; ++nj)
      madd[nj] = Mfg[(long)b * 1024 + s0 + nj * 16 + lanelo];

    __syncthreads();  // all waves done reading prev Ks/Vs
    // stage K tile: 128 x 64 (512 threads x 2 x uint4)
#pragma unroll
    for (int c = 0; c < 2; ++c) {
      int flat = c * 4096 + tid * 8;
      int row = flat >> 6, col = flat & 63;
      uint4 v = *(const uint4*)(Kh + head + (long)(s0 + row) * 64 + col);
      *(uint4*)&Ks[row * 72 + col] = v;
    }
    // stage V tile: 64 x 128 from Vt [d][1024]
#pragma unroll
    for (int c = 0; c < 2; ++c) {
      int flat = c * 4096 + tid * 8;
      int row = flat >> 7, col = flat & 127;
      uint4 v = *(const uint4*)(Vt + head + (long)row * 1024 + s0 + col);
      *(uint4*)&Vs[row * 136 + col] = v;
    }
    __syncthreads();

    // S init = bias + mask (log2 domain), folded into MFMA C-operand:
    // masked columns start at ~-1e30 and underflow to 0 in exp2.
    f32x4 S[8];
#pragma unroll
    for (int nj = 0; nj < 8; ++nj)
#pragma unroll
      for (int r = 0; r < 4; ++r)
        S[nj][r] = (float)bfr[nj >> 1][(nj & 1) * 4 + r] + madd[nj];

    // S += Q K^T (log2 domain)
#pragma unroll
    for (int ks = 0; ks < 2; ++ks) {
      bf16x8 bk[8];
#pragma unroll
      for (int nj = 0; nj < 8; ++nj)
        bk[nj] = *(const bf16x8*)(Ks + (nj * 16 + lanelo) * 72 + ks * 32 + quad * 8);
#pragma unroll
      for (int nj = 0; nj < 8; ++nj)
        S[nj] = __builtin_amdgcn_mfma_f32_16x16x32_bf16(aq[ks], bk[nj], S[nj], 0, 0, 0);
    }

    // online softmax (log2 domain). R11: max via shallow tree + 4 shfl (must
    // stay row-uniform for exp2); SUM kept as per-lane partial -- al is
    // row-uniform so lrow_partial scales identically; one reduce at epilogue.
#pragma unroll
    for (int r = 0; r < 4; ++r) {
      float m01 = fmaxf(S[0][r], S[1][r]);
      float m23 = fmaxf(S[2][r], S[3][r]);
      float m45 = fmaxf(S[4][r], S[5][r]);
      float m67 = fmaxf(S[6][r], S[7][r]);
      float mx = fmaxf(fmaxf(m01, m23), fmaxf(m45, m67));
      mx = fmaxf(mx, __shfl_xor(mx, 1, 16));
      mx = fmaxf(mx, __shfl_xor(mx, 2, 16));
      mx = fmaxf(mx, __shfl_xor(mx, 4, 16));
      mx = fmaxf(mx, __shfl_xor(mx, 8, 16));
      float mold = mrow[r];
      float mnew = fmaxf(mold, mx);
      float al = exp2f(mold - mnew);
      mrow[r] = mnew;
      float rs = 0.f;
#pragma unroll
      for (int nj = 0; nj < 8; ++nj) {
        float p = exp2f(S[nj][r] - mnew);
        S[nj][r] = p;
        rs += p;
      }
      lrow[r] = lrow[r] * al + rs;  // partial: this lane's 8 columns only
#pragma unroll
      for (int dj = 0; dj < 4; ++dj) Oacc[dj][r] *= al;
    }

    // O += P V, in two 64-col halves (P rows are wave-private: no barrier)
#pragma unroll
    for (int half = 0; half < 2; ++half) {
#pragma unroll
      for (int njl = 0; njl < 4; ++njl)
#pragma unroll
        for (int r = 0; r < 4; ++r)
          Ps[(wid * 16 + quad * 4 + r) * 72 + njl * 16 + lanelo] =
              f2bf(S[half * 4 + njl][r]);
#pragma unroll
      for (int ks2 = 0; ks2 < 2; ++ks2) {
        const int ks = half * 2 + ks2;
        bf16x8 ap, bv[4];
        ap = *(const bf16x8*)(Ps + (wid * 16 + lanelo) * 72 + ks2 * 32 + quad * 8);
#pragma unroll
        for (int dj = 0; dj < 4; ++dj)
          bv[dj] = *(const bf16x8*)(Vs + (dj * 16 + lanelo) * 136 + ks * 32 + quad * 8);
#pragma unroll
        for (int dj = 0; dj < 4; ++dj)
          Oacc[dj] = __builtin_amdgcn_mfma_f32_16x16x32_bf16(ap, bv[dj], Oacc[dj], 0, 0, 0);
      }
    }
  }

  // epilogue: reduce the partial row-sums once, then A2 = O / l
#pragma unroll
  for (int r = 0; r < 4; ++r) {
    float l = lrow[r];
    l += __shfl_xor(l, 1, 16);
    l += __shfl_xor(l, 2, 16);
    l += __shfl_xor(l, 4, 16);
    l += __shfl_xor(l, 8, 16);
    float rinv = __builtin_amdgcn_rcpf(l);
    int t = t0 + wid * 16 + quad * 4 + r;
#pragma unroll
    for (int dj = 0; dj < 4; ++dj) {
      int d = dj * 16 + lanelo;
      A2[(long)(t * 8 + b) * 1024 + h * 64 + d] = f2bf(Oacc[dj][r] * rinv);
    }
  }
}

// ---------------- out projection GEMM -> fp32 d_out ----------------
// XCD swizzle: 512 blocks, chunk 64/XCD -> 2MB A2-panel + 2MB WoT per L2.
__global__ __launch_bounds__(256, 2) void k_gemm_out(
    const unsigned short* __restrict__ A, const unsigned short* __restrict__ Bt,
    float* __restrict__ out) {
  __shared__ unsigned short As[128 * 32];
  __shared__ unsigned short Bs[128 * 32];
  f32x4 acc[4][4];
  const f32x4 z4 = {0.f, 0.f, 0.f, 0.f};
#pragma unroll
  for (int i = 0; i < 4; ++i)
#pragma unroll
    for (int j = 0; j < 4; ++j) acc[i][j] = z4;

  const int flat = blockIdx.y * 8 + blockIdx.x;
  const int swz = (flat & 7) * 64 + (flat >> 3);  // bijective (512%8==0)
  const long m0 = (long)(swz / 8) * 128;
  const long n0 = (long)(swz % 8) * 128;
  gemm_tile_128x128(A, Bt, 1024, m0, n0, As, Bs, acc);

  const int tid = threadIdx.x;
  const int wid = tid >> 6;
  const int lane = tid & 63;
  const int lanelo = lane & 15;
  const int quad = lane >> 4;
  const int wm = (wid >> 1) << 6;
  const int wn = (wid & 1) << 6;
#pragma unroll
  for (int mi = 0; mi < 4; ++mi)
#pragma unroll
    for (int nj = 0; nj < 4; ++nj)
#pragma unroll
      for (int r = 0; r < 4; ++r) {
        long m = m0 + wm + mi * 16 + quad * 4 + r;
        long n = n0 + wn + nj * 16 + lanelo;
        out[m * 1024 + n] = acc[mi][nj][r];
      }
}

// ---------------- launch ----------------
extern "C" void kernel_launch(void* const* d_in, const int* in_sizes, int n_in,
                              void* d_out, int out_size, void* d_ws, size_t ws_size,
                              hipStream_t stream) {
  const float* query = (const float*)d_in[0];
  const int* mask = (const int*)d_in[1];
  const float* bias = (const float*)d_in[2];
  const float* wq = (const float*)d_in[3];
  const float* wk = (const float*)d_in[4];
  const float* wv = (const float*)d_in[5];
  const float* wo = (const float*)d_in[6];
  float* out = (float*)d_out;

  char* ws = (char*)d_ws;
  const size_t MB = 1024 * 1024;
  unsigned short* Abuf  = (unsigned short*)(ws);             // 16 MB
  unsigned short* WqkvT = (unsigned short*)(ws + 16 * MB);   // 6 MB
  unsigned short* WoT   = (unsigned short*)(ws + 22 * MB);   // 2 MB
  unsigned short* Qh    = (unsigned short*)(ws + 24 * MB);   // 16 MB
  unsigned short* Kh    = (unsigned short*)(ws + 40 * MB);   // 16 MB
  unsigned short* Vt    = (unsigned short*)(ws + 56 * MB);   // 16 MB
  unsigned short* A2    = (unsigned short*)(ws + 72 * MB);   // 16 MB
  unsigned short* B2    = (unsigned short*)(ws + 88 * MB);   // 32 MB
  float*          Mfg   = (float*)(ws + 120 * MB);           // 32 KB

  k_cvt<<<dim3(8192), dim3(256), 0, stream>>>(query, Abuf);
  k_mask<<<dim3(32), dim3(256), 0, stream>>>(mask, Mfg);
  dim3 tb(32, 8);
  k_transw4<<<dim3(32, 32, 4), tb, 0, stream>>>(wq, wk, wv, wo, WqkvT, WoT);
  k_biasT<<<dim3(8, 8, 16), dim3(256), 0, stream>>>(bias, B2);
  k_gemm_qkv<<<dim3(24, 64), dim3(256), 0, stream>>>(Abuf, WqkvT, Qh, Kh, Vt);
  k_attn<<<dim3(128, 8), dim3(512), 0, stream>>>(Qh, Kh, Vt, B2, Mfg, A2);
  k_gemm_out<<<dim3(8, 64), dim3(256), 0, stream>>>(A2, WoT, out);
}

// Round 7
// 378.310 us; speedup vs baseline: 1.0258x; 1.0258x over previous
//
#include <hip/hip_runtime.h>

// ---------------------------------------------------------------------------
// MultiheadAttention: T=1024, B=8, E=1024, H=16, HD=64, SCALE=0.125
// R12: combine best-measured parts. k_attn = R8 verbatim (119.6us; R11's
//     softmax rewrite perturbed regalloc into spill, +17us - reverted).
//     Non-attn = R11 stack (XCD-chunked GEMM swizzle + fused transw4),
//     measured -11us vs R3. No new mechanisms this round.
// ---------------------------------------------------------------------------

typedef __bf16 bf16x8 __attribute__((ext_vector_type(8)));
typedef float f32x4 __attribute__((ext_vector_type(4)));

#define LOG2E 1.4426950408889634f
#define QSCALE 0.18033688011112042f  // 0.125 * LOG2E

// round-to-nearest-even (one-time prep kernels)
static __device__ __forceinline__ unsigned short f2bf_rn(float f) {
  union { float f; unsigned u; } x;
  x.f = f;
  unsigned r = (x.u + 0x7fffu + ((x.u >> 16) & 1u)) >> 16;
  return (unsigned short)r;
}
// round-half-up (hot paths: 2 VALU ops)
static __device__ __forceinline__ unsigned short f2bf(float f) {
  union { float f; unsigned u; } x;
  x.f = f;
  return (unsigned short)((x.u + 0x8000u) >> 16);
}

static __device__ __forceinline__ void async_cp16(const void* g, void* l) {
  __builtin_amdgcn_global_load_lds((__attribute__((address_space(1))) void*)g,
                                   (__attribute__((address_space(3))) void*)l,
                                   16, 0, 0);
}

// ---------------- fp32 -> bf16 convert (query) ----------------
__global__ void k_cvt(const float* __restrict__ src, unsigned short* __restrict__ dst) {
  const int idx = blockIdx.x * 256 + threadIdx.x;
  const float4 f = ((const float4*)src)[idx];
  unsigned lo = (unsigned)f2bf_rn(f.x) | ((unsigned)f2bf_rn(f.y) << 16);
  unsigned hi = (unsigned)f2bf_rn(f.z) | ((unsigned)f2bf_rn(f.w) << 16);
  uint2 v; v.x = lo; v.y = hi;
  *(uint2*)(dst + (size_t)idx * 4) = v;
}

// ---------------- mask -> additive float (0 / -1e30) ----------------
__global__ void k_mask(const int* __restrict__ mask, float* __restrict__ Mfg) {
  const int i = blockIdx.x * 256 + threadIdx.x;  // 8192 total
  Mfg[i] = mask[i] ? -1e30f : 0.f;
}

// ---------------- transpose + convert 4 weights in one launch --------------
__global__ void k_transw4(const float* __restrict__ wq, const float* __restrict__ wk,
                          const float* __restrict__ wv, const float* __restrict__ wo,
                          unsigned short* __restrict__ d_qkv,
                          unsigned short* __restrict__ d_o) {
  __shared__ float tile[32][33];
  const int z = blockIdx.z;
  const float* src = (z == 0) ? wq : (z == 1) ? wk : (z == 2) ? wv : wo;
  unsigned short* dst = (z < 3) ? d_qkv + (size_t)z * 1024 * 1024 : d_o;
  const int bx = blockIdx.x << 5;
  const int by = blockIdx.y << 5;
  const int tx = threadIdx.x, ty = threadIdx.y;
#pragma unroll
  for (int i = 0; i < 32; i += 8)
    tile[ty + i][tx] = src[(size_t)(by + ty + i) * 1024 + bx + tx];
  __syncthreads();
#pragma unroll
  for (int i = 0; i < 32; i += 8)
    dst[(size_t)(bx + ty + i) * 1024 + by + tx] = f2bf_rn(tile[tx][ty + i]);
}

// ---------------- bias pretransform: fragment-layout bf16, log2 domain -----
__global__ __launch_bounds__(256, 2) void k_biasT(const float* __restrict__ bias,
                                                  unsigned short* __restrict__ B2) {
  __shared__ unsigned short tile[128 * 132];
  const int tid = threadIdx.x;
  const int ss = blockIdx.x, tt = blockIdx.y, h = blockIdx.z;
  const float* src = bias + ((long)h * 1024 + tt * 128) * 1024 + ss * 128;
#pragma unroll
  for (int c = 0; c < 16; ++c) {
    int flat = c * 256 + tid;
    int row = flat >> 5, col = (flat & 31) << 2;
    float4 v = *(const float4*)(src + (long)row * 1024 + col);
    unsigned short* t4 = &tile[row * 132 + col];
    t4[0] = f2bf_rn(v.x * LOG2E); t4[1] = f2bf_rn(v.y * LOG2E);
    t4[2] = f2bf_rn(v.z * LOG2E); t4[3] = f2bf_rn(v.w * LOG2E);
  }
  __syncthreads();
  const int wid = tid >> 6, lane = tid & 63, lanelo = lane & 15, quad = lane >> 4;
  unsigned short outv[64];
#pragma unroll
  for (int mi = 0; mi < 2; ++mi)
#pragma unroll
    for (int nj = 0; nj < 8; ++nj)
#pragma unroll
      for (int r = 0; r < 4; ++r)
        outv[mi * 32 + nj * 4 + r] =
            tile[(wid * 32 + mi * 16 + quad * 4 + r) * 132 + nj * 16 + lanelo];
  unsigned short* dst = B2 + ((((long)(h * 8 + tt) * 8 + ss) * 256 + tid) << 6);
#pragma unroll
  for (int i = 0; i < 8; ++i) ((uint4*)dst)[i] = ((const uint4*)outv)[i];
}

// ---------------- 128x128 bf16 GEMM mainloop (m97 structure) ----------------
static __device__ __forceinline__ void gemm_tile_128x128(
    const unsigned short* __restrict__ A, const unsigned short* __restrict__ Bt,
    int K, long m0, long n0,
    unsigned short* As, unsigned short* Bs, f32x4 acc[4][4]) {
  const int tid = threadIdx.x;
  const int wid = tid >> 6;
  const int lane = tid & 63;
  const int lanelo = lane & 15;
  const int quad = lane >> 4;
  const int wm = (wid >> 1) << 6;
  const int wn = (wid & 1) << 6;
  const int srow = tid >> 2;
  const int scol = (tid & 3) << 3;

  for (int k0 = 0; k0 < K; k0 += 32) {
    __syncthreads();
    {
      const unsigned short* ga0 = A + (m0 + srow) * K + k0 + scol;
      const unsigned short* ga1 = A + (m0 + srow + 64) * K + k0 + scol;
      const unsigned short* gb0 = Bt + (n0 + srow) * K + k0 + scol;
      const unsigned short* gb1 = Bt + (n0 + srow + 64) * K + k0 + scol;
      char* la = (char*)As + wid * 1024;
      char* lb = (char*)Bs + wid * 1024;
      async_cp16(ga0, la);
      async_cp16(ga1, la + 4096);
      async_cp16(gb0, lb);
      async_cp16(gb1, lb + 4096);
    }
    __syncthreads();
    bf16x8 a[4], b[4];
#pragma unroll
    for (int i = 0; i < 4; ++i) {
      a[i] = *(const bf16x8*)(As + (wm + i * 16 + lanelo) * 32 + quad * 8);
      b[i] = *(const bf16x8*)(Bs + (wn + i * 16 + lanelo) * 32 + quad * 8);
    }
#pragma unroll
    for (int i = 0; i < 4; ++i)
#pragma unroll
      for (int j = 0; j < 4; ++j)
        acc[i][j] = __builtin_amdgcn_mfma_f32_16x16x32_bf16(a[i], b[j], acc[i][j], 0, 0, 0);
  }
}

// ---------------- QKV GEMM with scatter epilogue ----------------
// Qh/Kh: [bh][t][64] bf16 (Q pre-scaled by 0.125*LOG2E); Vt: [bh][d][1024].
// XCD swizzle: 1536 blocks, chunk 192/XCD -> 8 m-rows (2MB A-panel) per L2.
__global__ __launch_bounds__(256, 2) void k_gemm_qkv(
    const unsigned short* __restrict__ A, const unsigned short* __restrict__ Bt,
    unsigned short* __restrict__ Qh, unsigned short* __restrict__ Kh,
    unsigned short* __restrict__ Vt) {
  __shared__ unsigned short smem[9216];  // As(4096) + Bs(4096); V-epilogue reuses [128][72]
  unsigned short* As = smem;
  unsigned short* Bs = smem + 4096;
  f32x4 acc[4][4];
  const f32x4 z4 = {0.f, 0.f, 0.f, 0.f};
#pragma unroll
  for (int i = 0; i < 4; ++i)
#pragma unroll
    for (int j = 0; j < 4; ++j) acc[i][j] = z4;

  const int flat = blockIdx.y * 24 + blockIdx.x;        // HW dispatch order
  const int swz = (flat & 7) * 192 + (flat >> 3);       // bijective (1536%8==0)
  const int bx = swz % 24, by = swz / 24;
  const long m0 = (long)by * 128;
  const long n0 = (long)bx * 128;
  gemm_tile_128x128(A, Bt, 1024, m0, n0, As, Bs, acc);

  const int tid = threadIdx.x;
  const int wid = tid >> 6;
  const int lane = tid & 63;
  const int lanelo = lane & 15;
  const int quad = lane >> 4;
  const int wm = (wid >> 1) << 6;
  const int wn = (wid & 1) << 6;
  const int which = bx >> 3;  // 0:Q 1:K 2:V

  if (which == 2) {
    // V epilogue: LDS transpose -> 32B-run coalesced stores into Vt[bh][d][1024]
    unsigned short* Vt_s = smem;  // [128][72]
    const long t0g = m0 >> 3;
#pragma unroll
    for (int half = 0; half < 2; ++half) {
      __syncthreads();
      if ((wid & 1) == half) {
#pragma unroll
        for (int mi = 0; mi < 4; ++mi)
#pragma unroll
          for (int nj = 0; nj < 4; ++nj)
#pragma unroll
            for (int r = 0; r < 4; ++r)
              Vt_s[(wm + mi * 16 + quad * 4 + r) * 72 + nj * 16 + lanelo] =
                  f2bf(acc[mi][nj][r]);
      }
      __syncthreads();
      const int h = (((int)(n0 & 1023)) >> 6) + half;
#pragma unroll
      for (int pp = 0; pp < 2; ++pp) {
        int p = tid + pp * 256;
        int b = p >> 6, d = p & 63;
        long off = ((long)(b * 16 + h)) << 16;
        __attribute__((aligned(16))) unsigned short vals[16];
#pragma unroll
        for (int t = 0; t < 16; ++t) vals[t] = Vt_s[(t * 8 + b) * 72 + d];
        uint4* dst = (uint4*)(Vt + off + (long)d * 1024 + t0g);
        dst[0] = ((const uint4*)vals)[0];
        dst[1] = ((const uint4*)vals)[1];
      }
    }
  } else {
#pragma unroll
    for (int mi = 0; mi < 4; ++mi)
#pragma unroll
      for (int nj = 0; nj < 4; ++nj)
#pragma unroll
        for (int r = 0; r < 4; ++r) {
          int m = (int)m0 + wm + mi * 16 + quad * 4 + r;
          int n = (int)n0 + wn + nj * 16 + lanelo;
          float v = acc[mi][nj][r];
          int t = m >> 3, b = m & 7;
          int e = n & 1023, h = e >> 6, d = e & 63;
          long off = ((long)(b * 16 + h)) << 16;
          if (which == 0)
            Qh[off + t * 64 + d] = f2bf(v * QSCALE);
          else
            Kh[off + t * 64 + d] = f2bf(v);
        }
  }
}

// ---------------- flash attention (log2-domain, 512 thr / 16 rows per wave)
// grid: (128 bh, 8 t-tiles) — same-bh blocks share flat%8 -> same XCD L2.
// R8 version verbatim (best measured: 119.6us).
__global__ __launch_bounds__(512, 4) void k_attn(
    const unsigned short* __restrict__ Qh, const unsigned short* __restrict__ Kh,
    const unsigned short* __restrict__ Vt, const unsigned short* __restrict__ B2,
    const float* __restrict__ Mfg, unsigned short* __restrict__ A2) {
  __shared__ unsigned short Ks[128 * 72];  // [s_loc][64+8 pad]   18432 B
  __shared__ unsigned short Vs[64 * 136];  // [d][128+8 pad]      17408 B
  __shared__ unsigned short Ps[128 * 72];  // [t_loc][64+8 pad]   18432 B

  const int tid = threadIdx.x;
  const int wid = tid >> 6;        // 0..7
  const int lane = tid & 63;
  const int lanelo = lane & 15;
  const int quad = lane >> 4;
  const int bh = blockIdx.x;
  const int b = bh >> 4, h = bh & 15;
  const int tt = blockIdx.y;
  const int t0 = tt * 128;
  const long head = (long)bh << 16;

  // Q fragments straight from global (pre-scaled by 0.125*LOG2E): 16 rows/wave
  bf16x8 aq[2];
#pragma unroll
  for (int ks = 0; ks < 2; ++ks)
    aq[ks] = *(const bf16x8*)(Qh + head +
                              (long)(t0 + wid * 16 + lanelo) * 64 +
                              ks * 32 + quad * 8);

  const f32x4 z4 = {0.f, 0.f, 0.f, 0.f};
  f32x4 Oacc[4];
#pragma unroll
  for (int dj = 0; dj < 4; ++dj) Oacc[dj] = z4;
  float mrow[4], lrow[4];
#pragma unroll
  for (int r = 0; r < 4; ++r) { mrow[r] = -1e30f; lrow[r] = 0.f; }

  // bias fragment base: B2 laid out for 256-thr blocks with 2 mi-frags/thread;
  // wave pair (wid>>1) = old wid, (wid&1) = old mi.
  const long biasbase = (((long)(h * 8 + tt) * 8) * 256 + (wid >> 1) * 64 + lane) * 64 +
                        (wid & 1) * 32;

  for (int s0 = 0; s0 < 1024; s0 += 128) {
    // bias + mask loads: independent, issued before barriers for overlap
    bf16x8 bfr[4];
    {
      const bf16x8* bp8 = (const bf16x8*)(B2 + biasbase + ((long)(s0 >> 7) * 256 << 6));
#pragma unroll
      for (int i = 0; i < 4; ++i) bfr[i] = bp8[i];
    }
    float madd[8];
#pragma unroll
    for (int nj = 0; nj < 8; ++nj)
      madd[nj] = Mfg[(long)b * 1024 + s0 + nj * 16 + lanelo];

    __syncthreads();  // all waves done reading prev Ks/Vs
    // stage K tile: 128 x 64 (512 threads x 2 x uint4)
#pragma unroll
    for (int c = 0; c < 2; ++c) {
      int flat = c * 4096 + tid * 8;
      int row = flat >> 6, col = flat & 63;
      uint4 v = *(const uint4*)(Kh + head + (long)(s0 + row) * 64 + col);
      *(uint4*)&Ks[row * 72 + col] = v;
    }
    // stage V tile: 64 x 128 from Vt [d][1024]
#pragma unroll
    for (int c = 0; c < 2; ++c) {
      int flat = c * 4096 + tid * 8;
      int row = flat >> 7, col = flat & 127;
      uint4 v = *(const uint4*)(Vt + head + (long)row * 1024 + s0 + col);
      *(uint4*)&Vs[row * 136 + col] = v;
    }
    __syncthreads();

    // S init = bias + mask (log2 domain), folded into MFMA C-operand:
    // masked columns start at ~-1e30 and underflow to 0 in exp2.
    f32x4 S[8];
#pragma unroll
    for (int nj = 0; nj < 8; ++nj)
#pragma unroll
      for (int r = 0; r < 4; ++r)
        S[nj][r] = (float)bfr[nj >> 1][(nj & 1) * 4 + r] + madd[nj];

    // S += Q K^T (log2 domain)
#pragma unroll
    for (int ks = 0; ks < 2; ++ks) {
      bf16x8 bk[8];
#pragma unroll
      for (int nj = 0; nj < 8; ++nj)
        bk[nj] = *(const bf16x8*)(Ks + (nj * 16 + lanelo) * 72 + ks * 32 + quad * 8);
#pragma unroll
      for (int nj = 0; nj < 8; ++nj)
        S[nj] = __builtin_amdgcn_mfma_f32_16x16x32_bf16(aq[ks], bk[nj], S[nj], 0, 0, 0);
    }

    // online softmax per row (log2 domain; masked entries underflow to 0)
#pragma unroll
    for (int r = 0; r < 4; ++r) {
      float mx = S[0][r];
#pragma unroll
      for (int nj = 1; nj < 8; ++nj) mx = fmaxf(mx, S[nj][r]);
      mx = fmaxf(mx, __shfl_xor(mx, 1, 16));
      mx = fmaxf(mx, __shfl_xor(mx, 2, 16));
      mx = fmaxf(mx, __shfl_xor(mx, 4, 16));
      mx = fmaxf(mx, __shfl_xor(mx, 8, 16));
      float mold = mrow[r];
      float mnew = fmaxf(mold, mx);
      float al = exp2f(mold - mnew);
      mrow[r] = mnew;
      float rs = 0.f;
#pragma unroll
      for (int nj = 0; nj < 8; ++nj) {
        float p = exp2f(S[nj][r] - mnew);
        S[nj][r] = p;
        rs += p;
      }
      rs += __shfl_xor(rs, 1, 16);
      rs += __shfl_xor(rs, 2, 16);
      rs += __shfl_xor(rs, 4, 16);
      rs += __shfl_xor(rs, 8, 16);
      lrow[r] = lrow[r] * al + rs;
#pragma unroll
      for (int dj = 0; dj < 4; ++dj) Oacc[dj][r] *= al;
    }

    // O += P V, in two 64-col halves (P rows are wave-private: no barrier)
#pragma unroll
    for (int half = 0; half < 2; ++half) {
#pragma unroll
      for (int njl = 0; njl < 4; ++njl)
#pragma unroll
        for (int r = 0; r < 4; ++r)
          Ps[(wid * 16 + quad * 4 + r) * 72 + njl * 16 + lanelo] =
              f2bf(S[half * 4 + njl][r]);
#pragma unroll
      for (int ks2 = 0; ks2 < 2; ++ks2) {
        const int ks = half * 2 + ks2;
        bf16x8 ap, bv[4];
        ap = *(const bf16x8*)(Ps + (wid * 16 + lanelo) * 72 + ks2 * 32 + quad * 8);
#pragma unroll
        for (int dj = 0; dj < 4; ++dj)
          bv[dj] = *(const bf16x8*)(Vs + (dj * 16 + lanelo) * 136 + ks * 32 + quad * 8);
#pragma unroll
        for (int dj = 0; dj < 4; ++dj)
          Oacc[dj] = __builtin_amdgcn_mfma_f32_16x16x32_bf16(ap, bv[dj], Oacc[dj], 0, 0, 0);
      }
    }
  }

  // epilogue: A2[(t*8+b)*1024 + h*64 + d] = O / l
#pragma unroll
  for (int r = 0; r < 4; ++r) {
    float rinv = __builtin_amdgcn_rcpf(lrow[r]);
    int t = t0 + wid * 16 + quad * 4 + r;
#pragma unroll
    for (int dj = 0; dj < 4; ++dj) {
      int d = dj * 16 + lanelo;
      A2[(long)(t * 8 + b) * 1024 + h * 64 + d] = f2bf(Oacc[dj][r] * rinv);
    }
  }
}

// ---------------- out projection GEMM -> fp32 d_out ----------------
// XCD swizzle: 512 blocks, chunk 64/XCD -> 2MB A2-panel + 2MB WoT per L2.
__global__ __launch_bounds__(256, 2) void k_gemm_out(
    const unsigned short* __restrict__ A, const unsigned short* __restrict__ Bt,
    float* __restrict__ out) {
  __shared__ unsigned short As[128 * 32];
  __shared__ unsigned short Bs[128 * 32];
  f32x4 acc[4][4];
  const f32x4 z4 = {0.f, 0.f, 0.f, 0.f};
#pragma unroll
  for (int i = 0; i < 4; ++i)
#pragma unroll
    for (int j = 0; j < 4; ++j) acc[i][j] = z4;

  const int flat = blockIdx.y * 8 + blockIdx.x;
  const int swz = (flat & 7) * 64 + (flat >> 3);  // bijective (512%8==0)
  const long m0 = (long)(swz / 8) * 128;
  const long n0 = (long)(swz % 8) * 128;
  gemm_tile_128x128(A, Bt, 1024, m0, n0, As, Bs, acc);

  const int tid = threadIdx.x;
  const int wid = tid >> 6;
  const int lane = tid & 63;
  const int lanelo = lane & 15;
  const int quad = lane >> 4;
  const int wm = (wid >> 1) << 6;
  const int wn = (wid & 1) << 6;
#pragma unroll
  for (int mi = 0; mi < 4; ++mi)
#pragma unroll
    for (int nj = 0; nj < 4; ++nj)
#pragma unroll
      for (int r = 0; r < 4; ++r) {
        long m = m0 + wm + mi * 16 + quad * 4 + r;
        long n = n0 + wn + nj * 16 + lanelo;
        out[m * 1024 + n] = acc[mi][nj][r];
      }
}

// ---------------- launch ----------------
extern "C" void kernel_launch(void* const* d_in, const int* in_sizes, int n_in,
                              void* d_out, int out_size, void* d_ws, size_t ws_size,
                              hipStream_t stream) {
  const float* query = (const float*)d_in[0];
  const int* mask = (const int*)d_in[1];
  const float* bias = (const float*)d_in[2];
  const float* wq = (const float*)d_in[3];
  const float* wk = (const float*)d_in[4];
  const float* wv = (const float*)d_in[5];
  const float* wo = (const float*)d_in[6];
  float* out = (float*)d_out;

  char* ws = (char*)d_ws;
  const size_t MB = 1024 * 1024;
  unsigned short* Abuf  = (unsigned short*)(ws);             // 16 MB
  unsigned short* WqkvT = (unsigned short*)(ws + 16 * MB);   // 6 MB
  unsigned short* WoT   = (unsigned short*)(ws + 22 * MB);   // 2 MB
  unsigned short* Qh    = (unsigned short*)(ws + 24 * MB);   // 16 MB
  unsigned short* Kh    = (unsigned short*)(ws + 40 * MB);   // 16 MB
  unsigned short* Vt    = (unsigned short*)(ws + 56 * MB);   // 16 MB
  unsigned short* A2    = (unsigned short*)(ws + 72 * MB);   // 16 MB
  unsigned short* B2    = (unsigned short*)(ws + 88 * MB);   // 32 MB
  float*          Mfg   = (float*)(ws + 120 * MB);           // 32 KB

  k_cvt<<<dim3(8192), dim3(256), 0, stream>>>(query, Abuf);
  k_mask<<<dim3(32), dim3(256), 0, stream>>>(mask, Mfg);
  dim3 tb(32, 8);
  k_transw4<<<dim3(32, 32, 4), tb, 0, stream>>>(wq, wk, wv, wo, WqkvT, WoT);
  k_biasT<<<dim3(8, 8, 16), dim3(256), 0, stream>>>(bias, B2);
  k_gemm_qkv<<<dim3(24, 64), dim3(256), 0, stream>>>(Abuf, WqkvT, Qh, Kh, Vt);
  k_attn<<<dim3(128, 8), dim3(512), 0, stream>>>(Qh, Kh, Vt, B2, Mfg, A2);
  k_gemm_out<<<dim3(8, 64), dim3(256), 0, stream>>>(A2, WoT, out);
}

// Round 8
// 354.672 us; speedup vs baseline: 1.0942x; 1.0666x over previous
//
#include <hip/hip_runtime.h>

// ---------------------------------------------------------------------------
// MultiheadAttention: T=1024, B=8, E=1024, H=16, HD=64, SCALE=0.125
// R13: GEMM K-step 32 -> 64 (both GEMMs). K=1024 at BK=32 = 64 full-drain
//     barriers/block amortized over 16 MFMAs each; BK=64 halves that
//     (32 MFMAs per barrier pair), LDS 18->32KB (still under the ~4
//     blocks/CU VGPR limit; m132's BK=128 regression was at 64KB).
//     128B row stride would be a 16-way read conflict -> R10-verified
//     both-sides XOR swizzle (global src chunk ^(row&7), same XOR on
//     fragment reads; measured 0 conflicts). k_attn = R12 verbatim.
// ---------------------------------------------------------------------------

typedef __bf16 bf16x8 __attribute__((ext_vector_type(8)));
typedef float f32x4 __attribute__((ext_vector_type(4)));

#define LOG2E 1.4426950408889634f
#define QSCALE 0.18033688011112042f  // 0.125 * LOG2E

// round-to-nearest-even (one-time prep kernels)
static __device__ __forceinline__ unsigned short f2bf_rn(float f) {
  union { float f; unsigned u; } x;
  x.f = f;
  unsigned r = (x.u + 0x7fffu + ((x.u >> 16) & 1u)) >> 16;
  return (unsigned short)r;
}
// round-half-up (hot paths: 2 VALU ops)
static __device__ __forceinline__ unsigned short f2bf(float f) {
  union { float f; unsigned u; } x;
  x.f = f;
  return (unsigned short)((x.u + 0x8000u) >> 16);
}

static __device__ __forceinline__ void async_cp16(const void* g, void* l) {
  __builtin_amdgcn_global_load_lds((__attribute__((address_space(1))) void*)g,
                                   (__attribute__((address_space(3))) void*)l,
                                   16, 0, 0);
}

// ---------------- fp32 -> bf16 convert (query) ----------------
__global__ void k_cvt(const float* __restrict__ src, unsigned short* __restrict__ dst) {
  const int idx = blockIdx.x * 256 + threadIdx.x;
  const float4 f = ((const float4*)src)[idx];
  unsigned lo = (unsigned)f2bf_rn(f.x) | ((unsigned)f2bf_rn(f.y) << 16);
  unsigned hi = (unsigned)f2bf_rn(f.z) | ((unsigned)f2bf_rn(f.w) << 16);
  uint2 v; v.x = lo; v.y = hi;
  *(uint2*)(dst + (size_t)idx * 4) = v;
}

// ---------------- mask -> additive float (0 / -1e30) ----------------
__global__ void k_mask(const int* __restrict__ mask, float* __restrict__ Mfg) {
  const int i = blockIdx.x * 256 + threadIdx.x;  // 8192 total
  Mfg[i] = mask[i] ? -1e30f : 0.f;
}

// ---------------- transpose + convert 4 weights in one launch --------------
__global__ void k_transw4(const float* __restrict__ wq, const float* __restrict__ wk,
                          const float* __restrict__ wv, const float* __restrict__ wo,
                          unsigned short* __restrict__ d_qkv,
                          unsigned short* __restrict__ d_o) {
  __shared__ float tile[32][33];
  const int z = blockIdx.z;
  const float* src = (z == 0) ? wq : (z == 1) ? wk : (z == 2) ? wv : wo;
  unsigned short* dst = (z < 3) ? d_qkv + (size_t)z * 1024 * 1024 : d_o;
  const int bx = blockIdx.x << 5;
  const int by = blockIdx.y << 5;
  const int tx = threadIdx.x, ty = threadIdx.y;
#pragma unroll
  for (int i = 0; i < 32; i += 8)
    tile[ty + i][tx] = src[(size_t)(by + ty + i) * 1024 + bx + tx];
  __syncthreads();
#pragma unroll
  for (int i = 0; i < 32; i += 8)
    dst[(size_t)(bx + ty + i) * 1024 + by + tx] = f2bf_rn(tile[tx][ty + i]);
}

// ---------------- bias pretransform: fragment-layout bf16, log2 domain -----
__global__ __launch_bounds__(256, 2) void k_biasT(const float* __restrict__ bias,
                                                  unsigned short* __restrict__ B2) {
  __shared__ unsigned short tile[128 * 132];
  const int tid = threadIdx.x;
  const int ss = blockIdx.x, tt = blockIdx.y, h = blockIdx.z;
  const float* src = bias + ((long)h * 1024 + tt * 128) * 1024 + ss * 128;
#pragma unroll
  for (int c = 0; c < 16; ++c) {
    int flat = c * 256 + tid;
    int row = flat >> 5, col = (flat & 31) << 2;
    float4 v = *(const float4*)(src + (long)row * 1024 + col);
    unsigned short* t4 = &tile[row * 132 + col];
    t4[0] = f2bf_rn(v.x * LOG2E); t4[1] = f2bf_rn(v.y * LOG2E);
    t4[2] = f2bf_rn(v.z * LOG2E); t4[3] = f2bf_rn(v.w * LOG2E);
  }
  __syncthreads();
  const int wid = tid >> 6, lane = tid & 63, lanelo = lane & 15, quad = lane >> 4;
  unsigned short outv[64];
#pragma unroll
  for (int mi = 0; mi < 2; ++mi)
#pragma unroll
    for (int nj = 0; nj < 8; ++nj)
#pragma unroll
      for (int r = 0; r < 4; ++r)
        outv[mi * 32 + nj * 4 + r] =
            tile[(wid * 32 + mi * 16 + quad * 4 + r) * 132 + nj * 16 + lanelo];
  unsigned short* dst = B2 + ((((long)(h * 8 + tt) * 8 + ss) * 256 + tid) << 6);
#pragma unroll
  for (int i = 0; i < 8; ++i) ((uint4*)dst)[i] = ((const uint4*)outv)[i];
}

// ---------------- 128x128 bf16 GEMM mainloop, BK=64, XOR-swizzled LDS ------
// LDS content: tile[row][c8] = glob[row][c8 ^ (row&7)] (c8 = 8-short chunk).
// Staged via linear global_load_lds with pre-swizzled per-lane source col.
static __device__ __forceinline__ void gemm_tile_128x128(
    const unsigned short* __restrict__ A, const unsigned short* __restrict__ Bt,
    int K, long m0, long n0,
    unsigned short* As, unsigned short* Bs, f32x4 acc[4][4]) {
  const int tid = threadIdx.x;
  const int wid = tid >> 6;
  const int lane = tid & 63;
  const int lanelo = lane & 15;
  const int quad = lane >> 4;
  const int wm = (wid >> 1) << 6;
  const int wn = (wid & 1) << 6;
  const int srow = tid >> 3;                               // 0..31
  const int scol = (((tid & 7) ^ (srow & 7)) << 3);        // pre-swizzled src col

  for (int k0 = 0; k0 < K; k0 += 64) {
    __syncthreads();
    {
      char* la = (char*)As + (wid << 10);
      char* lb = (char*)Bs + (wid << 10);
#pragma unroll
      for (int c = 0; c < 4; ++c) {
        const unsigned short* ga = A + (m0 + srow + c * 32) * K + k0 + scol;
        const unsigned short* gb = Bt + (n0 + srow + c * 32) * K + k0 + scol;
        async_cp16(ga, la + c * 4096);
        async_cp16(gb, lb + c * 4096);
      }
    }
    __syncthreads();
#pragma unroll
    for (int kk = 0; kk < 2; ++kk) {
      bf16x8 a[4], b[4];
#pragma unroll
      for (int i = 0; i < 4; ++i) {
        const int ra = wm + i * 16 + lanelo;
        const int rb = wn + i * 16 + lanelo;
        a[i] = *(const bf16x8*)(As + ra * 64 + (((kk * 4 + quad) ^ (ra & 7)) << 3));
        b[i] = *(const bf16x8*)(Bs + rb * 64 + (((kk * 4 + quad) ^ (rb & 7)) << 3));
      }
#pragma unroll
      for (int i = 0; i < 4; ++i)
#pragma unroll
        for (int j = 0; j < 4; ++j)
          acc[i][j] = __builtin_amdgcn_mfma_f32_16x16x32_bf16(a[i], b[j], acc[i][j], 0, 0, 0);
    }
  }
}

// ---------------- QKV GEMM with scatter epilogue ----------------
// Qh/Kh: [bh][t][64] bf16 (Q pre-scaled by 0.125*LOG2E); Vt: [bh][d][1024].
// XCD swizzle: 1536 blocks, chunk 192/XCD -> 8 m-rows (2MB A-panel) per L2.
__global__ __launch_bounds__(256, 2) void k_gemm_qkv(
    const unsigned short* __restrict__ A, const unsigned short* __restrict__ Bt,
    unsigned short* __restrict__ Qh, unsigned short* __restrict__ Kh,
    unsigned short* __restrict__ Vt) {
  __shared__ unsigned short smem[16384];  // As(8K shorts) + Bs(8K); V-epi reuses [128][72]
  unsigned short* As = smem;
  unsigned short* Bs = smem + 8192;
  f32x4 acc[4][4];
  const f32x4 z4 = {0.f, 0.f, 0.f, 0.f};
#pragma unroll
  for (int i = 0; i < 4; ++i)
#pragma unroll
    for (int j = 0; j < 4; ++j) acc[i][j] = z4;

  const int flat = blockIdx.y * 24 + blockIdx.x;        // HW dispatch order
  const int swz = (flat & 7) * 192 + (flat >> 3);       // bijective (1536%8==0)
  const int bx = swz % 24, by = swz / 24;
  const long m0 = (long)by * 128;
  const long n0 = (long)bx * 128;
  gemm_tile_128x128(A, Bt, 1024, m0, n0, As, Bs, acc);

  const int tid = threadIdx.x;
  const int wid = tid >> 6;
  const int lane = tid & 63;
  const int lanelo = lane & 15;
  const int quad = lane >> 4;
  const int wm = (wid >> 1) << 6;
  const int wn = (wid & 1) << 6;
  const int which = bx >> 3;  // 0:Q 1:K 2:V

  if (which == 2) {
    // V epilogue: LDS transpose -> 32B-run coalesced stores into Vt[bh][d][1024]
    unsigned short* Vt_s = smem;  // [128][72]
    const long t0g = m0 >> 3;
#pragma unroll
    for (int half = 0; half < 2; ++half) {
      __syncthreads();
      if ((wid & 1) == half) {
#pragma unroll
        for (int mi = 0; mi < 4; ++mi)
#pragma unroll
          for (int nj = 0; nj < 4; ++nj)
#pragma unroll
            for (int r = 0; r < 4; ++r)
              Vt_s[(wm + mi * 16 + quad * 4 + r) * 72 + nj * 16 + lanelo] =
                  f2bf(acc[mi][nj][r]);
      }
      __syncthreads();
      const int h = (((int)(n0 & 1023)) >> 6) + half;
#pragma unroll
      for (int pp = 0; pp < 2; ++pp) {
        int p = tid + pp * 256;
        int b = p >> 6, d = p & 63;
        long off = ((long)(b * 16 + h)) << 16;
        __attribute__((aligned(16))) unsigned short vals[16];
#pragma unroll
        for (int t = 0; t < 16; ++t) vals[t] = Vt_s[(t * 8 + b) * 72 + d];
        uint4* dst = (uint4*)(Vt + off + (long)d * 1024 + t0g);
        dst[0] = ((const uint4*)vals)[0];
        dst[1] = ((const uint4*)vals)[1];
      }
    }
  } else {
#pragma unroll
    for (int mi = 0; mi < 4; ++mi)
#pragma unroll
      for (int nj = 0; nj < 4; ++nj)
#pragma unroll
        for (int r = 0; r < 4; ++r) {
          int m = (int)m0 + wm + mi * 16 + quad * 4 + r;
          int n = (int)n0 + wn + nj * 16 + lanelo;
          float v = acc[mi][nj][r];
          int t = m >> 3, b = m & 7;
          int e = n & 1023, h = e >> 6, d = e & 63;
          long off = ((long)(b * 16 + h)) << 16;
          if (which == 0)
            Qh[off + t * 64 + d] = f2bf(v * QSCALE);
          else
            Kh[off + t * 64 + d] = f2bf(v);
        }
  }
}

// ---------------- flash attention (log2-domain, 512 thr / 16 rows per wave)
// grid: (128 bh, 8 t-tiles) — same-bh blocks share flat%8 -> same XCD L2.
// R8/R12 version verbatim (best measured: 119.6-121us).
__global__ __launch_bounds__(512, 4) void k_attn(
    const unsigned short* __restrict__ Qh, const unsigned short* __restrict__ Kh,
    const unsigned short* __restrict__ Vt, const unsigned short* __restrict__ B2,
    const float* __restrict__ Mfg, unsigned short* __restrict__ A2) {
  __shared__ unsigned short Ks[128 * 72];  // [s_loc][64+8 pad]   18432 B
  __shared__ unsigned short Vs[64 * 136];  // [d][128+8 pad]      17408 B
  __shared__ unsigned short Ps[128 * 72];  // [t_loc][64+8 pad]   18432 B

  const int tid = threadIdx.x;
  const int wid = tid >> 6;        // 0..7
  const int lane = tid & 63;
  const int lanelo = lane & 15;
  const int quad = lane >> 4;
  const int bh = blockIdx.x;
  const int b = bh >> 4, h = bh & 15;
  const int tt = blockIdx.y;
  const int t0 = tt * 128;
  const long head = (long)bh << 16;

  // Q fragments straight from global (pre-scaled by 0.125*LOG2E): 16 rows/wave
  bf16x8 aq[2];
#pragma unroll
  for (int ks = 0; ks < 2; ++ks)
    aq[ks] = *(const bf16x8*)(Qh + head +
                              (long)(t0 + wid * 16 + lanelo) * 64 +
                              ks * 32 + quad * 8);

  const f32x4 z4 = {0.f, 0.f, 0.f, 0.f};
  f32x4 Oacc[4];
#pragma unroll
  for (int dj = 0; dj < 4; ++dj) Oacc[dj] = z4;
  float mrow[4], lrow[4];
#pragma unroll
  for (int r = 0; r < 4; ++r) { mrow[r] = -1e30f; lrow[r] = 0.f; }

  // bias fragment base: B2 laid out for 256-thr blocks with 2 mi-frags/thread;
  // wave pair (wid>>1) = old wid, (wid&1) = old mi.
  const long biasbase = (((long)(h * 8 + tt) * 8) * 256 + (wid >> 1) * 64 + lane) * 64 +
                        (wid & 1) * 32;

  for (int s0 = 0; s0 < 1024; s0 += 128) {
    // bias + mask loads: independent, issued before barriers for overlap
    bf16x8 bfr[4];
    {
      const bf16x8* bp8 = (const bf16x8*)(B2 + biasbase + ((long)(s0 >> 7) * 256 << 6));
#pragma unroll
      for (int i = 0; i < 4; ++i) bfr[i] = bp8[i];
    }
    float madd[8];
#pragma unroll
    for (int nj = 0; nj < 8; ++nj)
      madd[nj] = Mfg[(long)b * 1024 + s0 + nj * 16 + lanelo];

    __syncthreads();  // all waves done reading prev Ks/Vs
    // stage K tile: 128 x 64 (512 threads x 2 x uint4)
#pragma unroll
    for (int c = 0; c < 2; ++c) {
      int flat = c * 4096 + tid * 8;
      int row = flat >> 6, col = flat & 63;
      uint4 v = *(const uint4*)(Kh + head + (long)(s0 + row) * 64 + col);
      *(uint4*)&Ks[row * 72 + col] = v;
    }
    // stage V tile: 64 x 128 from Vt [d][1024]
#pragma unroll
    for (int c = 0; c < 2; ++c) {
      int flat = c * 4096 + tid * 8;
      int row = flat >> 7, col = flat & 127;
      uint4 v = *(const uint4*)(Vt + head + (long)row * 1024 + s0 + col);
      *(uint4*)&Vs[row * 136 + col] = v;
    }
    __syncthreads();

    // S init = bias + mask (log2 domain), folded into MFMA C-operand:
    // masked columns start at ~-1e30 and underflow to 0 in exp2.
    f32x4 S[8];
#pragma unroll
    for (int nj = 0; nj < 8; ++nj)
#pragma unroll
      for (int r = 0; r < 4; ++r)
        S[nj][r] = (float)bfr[nj >> 1][(nj & 1) * 4 + r] + madd[nj];

    // S += Q K^T (log2 domain)
#pragma unroll
    for (int ks = 0; ks < 2; ++ks) {
      bf16x8 bk[8];
#pragma unroll
      for (int nj = 0; nj < 8; ++nj)
        bk[nj] = *(const bf16x8*)(Ks + (nj * 16 + lanelo) * 72 + ks * 32 + quad * 8);
#pragma unroll
      for (int nj = 0; nj < 8; ++nj)
        S[nj] = __builtin_amdgcn_mfma_f32_16x16x32_bf16(aq[ks], bk[nj], S[nj], 0, 0, 0);
    }

    // online softmax per row (log2 domain; masked entries underflow to 0)
#pragma unroll
    for (int r = 0; r < 4; ++r) {
      float mx = S[0][r];
#pragma unroll
      for (int nj = 1; nj < 8; ++nj) mx = fmaxf(mx, S[nj][r]);
      mx = fmaxf(mx, __shfl_xor(mx, 1, 16));
      mx = fmaxf(mx, __shfl_xor(mx, 2, 16));
      mx = fmaxf(mx, __shfl_xor(mx, 4, 16));
      mx = fmaxf(mx, __shfl_xor(mx, 8, 16));
      float mold = mrow[r];
      float mnew = fmaxf(mold, mx);
      float al = exp2f(mold - mnew);
      mrow[r] = mnew;
      float rs = 0.f;
#pragma unroll
      for (int nj = 0; nj < 8; ++nj) {
        float p = exp2f(S[nj][r] - mnew);
        S[nj][r] = p;
        rs += p;
      }
      rs += __shfl_xor(rs, 1, 16);
      rs += __shfl_xor(rs, 2, 16);
      rs += __shfl_xor(rs, 4, 16);
      rs += __shfl_xor(rs, 8, 16);
      lrow[r] = lrow[r] * al + rs;
#pragma unroll
      for (int dj = 0; dj < 4; ++dj) Oacc[dj][r] *= al;
    }

    // O += P V, in two 64-col halves (P rows are wave-private: no barrier)
#pragma unroll
    for (int half = 0; half < 2; ++half) {
#pragma unroll
      for (int njl = 0; njl < 4; ++njl)
#pragma unroll
        for (int r = 0; r < 4; ++r)
          Ps[(wid * 16 + quad * 4 + r) * 72 + njl * 16 + lanelo] =
              f2bf(S[half * 4 + njl][r]);
#pragma unroll
      for (int ks2 = 0; ks2 < 2; ++ks2) {
        const int ks = half * 2 + ks2;
        bf16x8 ap, bv[4];
        ap = *(const bf16x8*)(Ps + (wid * 16 + lanelo) * 72 + ks2 * 32 + quad * 8);
#pragma unroll
        for (int dj = 0; dj < 4; ++dj)
          bv[dj] = *(const bf16x8*)(Vs + (dj * 16 + lanelo) * 136 + ks * 32 + quad * 8);
#pragma unroll
        for (int dj = 0; dj < 4; ++dj)
          Oacc[dj] = __builtin_amdgcn_mfma_f32_16x16x32_bf16(ap, bv[dj], Oacc[dj], 0, 0, 0);
      }
    }
  }

  // epilogue: A2[(t*8+b)*1024 + h*64 + d] = O / l
#pragma unroll
  for (int r = 0; r < 4; ++r) {
    float rinv = __builtin_amdgcn_rcpf(lrow[r]);
    int t = t0 + wid * 16 + quad * 4 + r;
#pragma unroll
    for (int dj = 0; dj < 4; ++dj) {
      int d = dj * 16 + lanelo;
      A2[(long)(t * 8 + b) * 1024 + h * 64 + d] = f2bf(Oacc[dj][r] * rinv);
    }
  }
}

// ---------------- out projection GEMM -> fp32 d_out ----------------
// XCD swizzle: 512 blocks, chunk 64/XCD -> 2MB A2-panel + 2MB WoT per L2.
__global__ __launch_bounds__(256, 2) void k_gemm_out(
    const unsigned short* __restrict__ A, const unsigned short* __restrict__ Bt,
    float* __restrict__ out) {
  __shared__ unsigned short As[128 * 64];
  __shared__ unsigned short Bs[128 * 64];
  f32x4 acc[4][4];
  const f32x4 z4 = {0.f, 0.f, 0.f, 0.f};
#pragma unroll
  for (int i = 0; i < 4; ++i)
#pragma unroll
    for (int j = 0; j < 4; ++j) acc[i][j] = z4;

  const int flat = blockIdx.y * 8 + blockIdx.x;
  const int swz = (flat & 7) * 64 + (flat >> 3);  // bijective (512%8==0)
  const long m0 = (long)(swz / 8) * 128;
  const long n0 = (long)(swz % 8) * 128;
  gemm_tile_128x128(A, Bt, 1024, m0, n0, As, Bs, acc);

  const int tid = threadIdx.x;
  const int wid = tid >> 6;
  const int lane = tid & 63;
  const int lanelo = lane & 15;
  const int quad = lane >> 4;
  const int wm = (wid >> 1) << 6;
  const int wn = (wid & 1) << 6;
#pragma unroll
  for (int mi = 0; mi < 4; ++mi)
#pragma unroll
    for (int nj = 0; nj < 4; ++nj)
#pragma unroll
      for (int r = 0; r < 4; ++r) {
        long m = m0 + wm + mi * 16 + quad * 4 + r;
        long n = n0 + wn + nj * 16 + lanelo;
        out[m * 1024 + n] = acc[mi][nj][r];
      }
}

// ---------------- launch ----------------
extern "C" void kernel_launch(void* const* d_in, const int* in_sizes, int n_in,
                              void* d_out, int out_size, void* d_ws, size_t ws_size,
                              hipStream_t stream) {
  const float* query = (const float*)d_in[0];
  const int* mask = (const int*)d_in[1];
  const float* bias = (const float*)d_in[2];
  const float* wq = (const float*)d_in[3];
  const float* wk = (const float*)d_in[4];
  const float* wv = (const float*)d_in[5];
  const float* wo = (const float*)d_in[6];
  float* out = (float*)d_out;

  char* ws = (char*)d_ws;
  const size_t MB = 1024 * 1024;
  unsigned short* Abuf  = (unsigned short*)(ws);             // 16 MB
  unsigned short* WqkvT = (unsigned short*)(ws + 16 * MB);   // 6 MB
  unsigned short* WoT   = (unsigned short*)(ws + 22 * MB);   // 2 MB
  unsigned short* Qh    = (unsigned short*)(ws + 24 * MB);   // 16 MB
  unsigned short* Kh    = (unsigned short*)(ws + 40 * MB);   // 16 MB
  unsigned short* Vt    = (unsigned short*)(ws + 56 * MB);   // 16 MB
  unsigned short* A2    = (unsigned short*)(ws + 72 * MB);   // 16 MB
  unsigned short* B2    = (unsigned short*)(ws + 88 * MB);   // 32 MB
  float*          Mfg   = (float*)(ws + 120 * MB);           // 32 KB

  k_cvt<<<dim3(8192), dim3(256), 0, stream>>>(query, Abuf);
  k_mask<<<dim3(32), dim3(256), 0, stream>>>(mask, Mfg);
  dim3 tb(32, 8);
  k_transw4<<<dim3(32, 32, 4), tb, 0, stream>>>(wq, wk, wv, wo, WqkvT, WoT);
  k_biasT<<<dim3(8, 8, 16), dim3(256), 0, stream>>>(bias, B2);
  k_gemm_qkv<<<dim3(24, 64), dim3(256), 0, stream>>>(Abuf, WqkvT, Qh, Kh, Vt);
  k_attn<<<dim3(128, 8), dim3(512), 0, stream>>>(Qh, Kh, Vt, B2, Mfg, A2);
  k_gemm_out<<<dim3(8, 64), dim3(256), 0, stream>>>(A2, WoT, out);
}